// Round 2
// baseline (218.717 us; speedup 1.0000x reference)
//
#include <hip/hip_runtime.h>
#include <math.h>

// Problem constants (match reference)
constexpr int C  = 6;
constexpr int NR = 2048;
constexpr int NC = 2048;
constexpr int KS = 10;
constexpr int PAD = 4;               // top/left circular halo

// Tiling: 64x64 outputs per block, single LDS buffer for the H-pass result.
constexpr int TX = 64;
constexpr int TY = 64;
constexpr int HT_H = TY + KS - 1;    // 73 H-rows needed per tile

__device__ __constant__ float MTFf[C] = {0.38f, 0.34f, 0.34f, 0.26f, 0.22f, 0.23f};

__global__ __launch_bounds__(256)
void s2_gaussian_blur_kernel(const float* __restrict__ x, float* __restrict__ out)
{
    // Single LDS buffer: horizontal-pass intermediate. 73*64*4 = 18.7 KB
    // -> ~6-8 blocks/CU (vs 3 with the old 41.5 KB double-buffer scheme).
    __shared__ float Ht[HT_H * TX];

    const int tid = threadIdx.x;
    const int c   = blockIdx.z;
    const int i0  = blockIdx.y * TY;
    const int j0  = blockIdx.x * TX;

    const float* xc = x   + (size_t)c * NR * NC;
    float*       oc = out + (size_t)c * NR * NC;

    // ---- per-thread fp32 weights (no barrier needed; err ~1e-6 << 3.25e-2) ----
    float w[KS];
    {
        float mtf    = MTFf[c];
        float sig    = 2.0f * sqrtf(-2.0f * logf(mtf) / (float)(M_PI * M_PI));
        float inv2s2 = 1.0f / (2.0f * sig * sig);
        float s = 0.0f;
        #pragma unroll
        for (int d = 0; d < KS; ++d) {
            float cd = -4.5f + (float)d;
            w[d] = expf(-cd * cd * inv2s2);
            s += w[d];
        }
        #pragma unroll
        for (int d = 0; d < KS; ++d) w[d] /= s;
    }

    // ---- Phase 1: horizontal pass, global -> LDS ----
    // item (r,g): H row r (global row i0+r-4), output cols [8g, 8g+8) of the tile.
    // Reads 17 input floats, writes 8 H values (2x ds_write_b128).
    // Interior col-blocks (bx in [1,30]) take an aligned float4 fast path.
    const bool interior = (blockIdx.x >= 1) && (blockIdx.x <= (NC / TX) - 2);

    for (int item = tid; item < HT_H * (TX / 8); item += 256) {
        const int r = item >> 3;
        const int g = item & 7;
        const int gr = (i0 + r - PAD + NR) & (NR - 1);
        const float* row = xc + (size_t)gr * NC;

        float v[17];
        if (interior) {
            // (j0 + 8g - 4)*4 bytes is 16B-aligned: j0 % 64 == 0, 8g*4 = 32B mult.
            const float4* p = (const float4*)(row + j0 + 8 * g - PAD);
            float4 a = p[0], b = p[1], d2 = p[2], d3 = p[3];
            v[0]=a.x;  v[1]=a.y;  v[2]=a.z;  v[3]=a.w;
            v[4]=b.x;  v[5]=b.y;  v[6]=b.z;  v[7]=b.w;
            v[8]=d2.x; v[9]=d2.y; v[10]=d2.z; v[11]=d2.w;
            v[12]=d3.x; v[13]=d3.y; v[14]=d3.z; v[15]=d3.w;
            v[16] = row[j0 + 8 * g + 12];
        } else {
            #pragma unroll
            for (int k = 0; k < 17; ++k)
                v[k] = row[(j0 + 8 * g + k - PAD + NC) & (NC - 1)];
        }

        float acc[8];
        #pragma unroll
        for (int o = 0; o < 8; ++o) {
            float a = 0.0f;
            #pragma unroll
            for (int d = 0; d < KS; ++d) a = fmaf(w[d], v[o + d], a);
            acc[o] = a;
        }
        float4* q = (float4*)&Ht[r * TX + 8 * g];
        q[0] = make_float4(acc[0], acc[1], acc[2], acc[3]);
        q[1] = make_float4(acc[4], acc[5], acc[6], acc[7]);
    }

    __syncthreads();

    // ---- Phase 2: vertical pass, LDS -> global ----
    // Thread owns a 4x4 output micro-tile: 13 ds_read_b128 row-reads (streamed,
    // conflict-free), 160 FMA, 4 coalesced float4 stores. Exactly 256 items.
    {
        const int cg = tid & 15;    // column group: cols [4*cg, 4*cg+4)
        const int rg = tid >> 4;    // row group:    rows [4*rg, 4*rg+4)
        float acc[4][4] = {{0.f}};

        #pragma unroll
        for (int k = 0; k < 13; ++k) {
            float4 h = *(const float4*)&Ht[(rg * 4 + k) * TX + cg * 4];
            #pragma unroll
            for (int o = 0; o < 4; ++o) {
                const int d = k - o;
                if (d >= 0 && d < KS) {
                    acc[o][0] = fmaf(w[d], h.x, acc[o][0]);
                    acc[o][1] = fmaf(w[d], h.y, acc[o][1]);
                    acc[o][2] = fmaf(w[d], h.z, acc[o][2]);
                    acc[o][3] = fmaf(w[d], h.w, acc[o][3]);
                }
            }
        }

        #pragma unroll
        for (int o = 0; o < 4; ++o) {
            float4* q = (float4*)&oc[(size_t)(i0 + rg * 4 + o) * NC + (j0 + cg * 4)];
            *q = make_float4(acc[o][0], acc[o][1], acc[o][2], acc[o][3]);
        }
    }
}

extern "C" void kernel_launch(void* const* d_in, const int* in_sizes, int n_in,
                              void* d_out, int out_size, void* d_ws, size_t ws_size,
                              hipStream_t stream) {
    const float* x = (const float*)d_in[0];
    float* out = (float*)d_out;
    dim3 grid(NC / TX, NR / TY, C);   // 32 x 32 x 6 = 6144 blocks
    dim3 block(256);
    s2_gaussian_blur_kernel<<<grid, block, 0, stream>>>(x, out);
}